// Round 3
// baseline (215.945 us; speedup 1.0000x reference)
//
#include <hip/hip_runtime.h>

// LR_PINN_phase2_midout: fused 4-stage tiny MLP, N=262144, H=256, R=32.
// R3 = R2 + __launch_bounds__(1024, 4).
// R2's counters showed VGPR_Count=64 and 274MB FETCH / 138MB WRITE: the
// allocator (absent a waves-per-EU hint) capped VGPRs at 64 and spilled the
// entire register-resident h-fragment chain to scratch. 4 waves/EU declared
// -> 128 VGPR cap -> the ~100-live-reg layout-closed design fits, zero spill.
//
// Design recap: mfma_f32_16x16x16f16 everywhere. With K=16, the MFMA C/D
// layout (col = lane&15 = point, row = 4*quad + reg) is IDENTICAL to the next
// MFMA's B-fragment layout, so phase0 -> GEMM1 -> GEMM2 -> tanh -> ... is
// layout-closed in registers: zero LDS round-trips, zero barriers, zero
// cross-lane ops until the final 2-shuffle epilogue reduce. LDS holds only
// the fp16 weights (109 KB, conflict-free strides) -> 1024-thread block/CU.

typedef _Float16 half4_t __attribute__((ext_vector_type(4)));
typedef float    float4_t __attribute__((ext_vector_type(4)));

#define CT_S 260   // halfs; 130 dwords/row; bank(2m%32) -> 16 distinct b64 bank-pairs
#define RW_S 36    // halfs; 18 dwords/row;  bank(18m%32) distinct (gcd(18,32)=2) -> conflict-free

namespace {

struct Smem {
  _Float16 ct[3][32 * CT_S];    // Ct[r][j] = col_k[j][r]*alpha_k[r]  (49.9 KB)
  _Float16 rw[3][256 * RW_S];   // R[j][r]                            (55.3 KB)
  float w0[256], w1[256], bb[256], ew[256];                           // (4 KB)
};

__device__ __forceinline__ float fast_tanh(float x) {
  // tanh(x) = 1 - 2/(1 + exp2(2*log2e*x)); exact saturation at +-inf.
  float e = __builtin_amdgcn_exp2f(x * 2.885390081777927f);
  return 1.0f - 2.0f * __builtin_amdgcn_rcpf(e + 1.0f);
}

__global__ __launch_bounds__(1024, 4) void pinn_fused(
    const float* __restrict__ xg, const float* __restrict__ tg,
    const float* __restrict__ sw, const float* __restrict__ sb,
    const float* __restrict__ ewp, const float* __restrict__ ebp,
    const float* __restrict__ c0, const float* __restrict__ c1,
    const float* __restrict__ c2, const float* __restrict__ r0,
    const float* __restrict__ r1, const float* __restrict__ r2,
    const float* __restrict__ a0, const float* __restrict__ a1,
    const float* __restrict__ a2, float* __restrict__ out, int n)
{
  __shared__ Smem sm;
  const int tid = threadIdx.x;

  // ---- stage weights fp32 -> fp16 LDS (once per block) ----
  for (int k = 0; k < 3; ++k) {
    const float* ck = (k == 0) ? c0 : (k == 1) ? c1 : c2;
    const float* rk = (k == 0) ? r0 : (k == 1) ? r1 : r2;
    const float* ak = (k == 0) ? a0 : (k == 1) ? a1 : a2;
    for (int i = tid; i < 8192; i += 1024) {
      const int j = i >> 5, r = i & 31;
      sm.ct[k][r * CT_S + j] = (_Float16)(ck[i] * ak[r]);  // fold diag(alpha)
      sm.rw[k][j * RW_S + r] = (_Float16)rk[i];
    }
  }
  if (tid < 256) {
    sm.w0[tid] = sw[2 * tid];
    sm.w1[tid] = sw[2 * tid + 1];
    sm.bb[tid] = sb[tid];
    sm.ew[tid] = ewp[tid];
  }
  __syncthreads();  // the only barrier

  const int wave = tid >> 6;
  const int lane = tid & 63;
  const int m = lane & 15;   // point index (MFMA col / A-row / B-col = lane&15)
  const int q = lane >> 4;   // quad
  const float ebv = ebp[0];

  const int ct0 = m * CT_S + 4 * q;         // Ct rows 0..15  (acc0), + 16*t
  const int ct1 = (16 + m) * CT_S + 4 * q;  // Ct rows 16..31 (acc1), + 16*t
  const int rwo = m * RW_S + 4 * q;         // R row 16t+m: + 576*t (RW_S*16)
  const int wo  = 4 * q;                    // j = 16t + 4q + jj
  const int tiles = n >> 4;

  for (int g = blockIdx.x * 16 + wave; g < tiles; g += 4096) {
    const int n0 = g * 16;
    const float xm = xg[n0 + m];
    const float tm = tg[n0 + m];

    // ---- phase 0: h[m][16t+4q+jj] = tanh(x*w0+t*w1+b), directly in B-frag layout ----
    half4_t hb[16];
#pragma unroll
    for (int t = 0; t < 16; ++t) {
      const int cb = t * 16 + wo;
      const float4_t w0v = *(const float4_t*)&sm.w0[cb];  // broadcast reads, conflict-free
      const float4_t w1v = *(const float4_t*)&sm.w1[cb];
      const float4_t bv  = *(const float4_t*)&sm.bb[cb];
      half4_t h;
      h.x = (_Float16)fast_tanh(fmaf(xm, w0v.x, fmaf(tm, w1v.x, bv.x)));
      h.y = (_Float16)fast_tanh(fmaf(xm, w0v.y, fmaf(tm, w1v.y, bv.y)));
      h.z = (_Float16)fast_tanh(fmaf(xm, w0v.z, fmaf(tm, w1v.z, bv.z)));
      h.w = (_Float16)fast_tanh(fmaf(xm, w0v.w, fmaf(tm, w1v.w, bv.w)));
      hb[t] = h;
    }

    float ssum = 0.0f;
#pragma unroll 1
    for (int k = 0; k < 3; ++k) {
      const _Float16* ctk = sm.ct[k];
      const _Float16* rwk = sm.rw[k];

      // ---- GEMM1: P^T[32 x 16pts] = Ct . h^T, K=256 in 16 K-tiles ----
      float4_t acc0 = {0.f, 0.f, 0.f, 0.f};
      float4_t acc1 = {0.f, 0.f, 0.f, 0.f};
#pragma unroll
      for (int t = 0; t < 16; ++t) {
        const half4_t a0 = *(const half4_t*)&ctk[ct0 + 16 * t];
        const half4_t a1 = *(const half4_t*)&ctk[ct1 + 16 * t];
        acc0 = __builtin_amdgcn_mfma_f32_16x16x16f16(a0, hb[t], acc0, 0, 0, 0);
        acc1 = __builtin_amdgcn_mfma_f32_16x16x16f16(a1, hb[t], acc1, 0, 0, 0);
      }
      // D(acc0/acc1) is ALREADY the B-frag for GEMM2 (r = 4q+reg) -> just pack fp16.
      const half4_t pfA = {(_Float16)acc0.x, (_Float16)acc0.y, (_Float16)acc0.z, (_Float16)acc0.w};
      const half4_t pfB = {(_Float16)acc1.x, (_Float16)acc1.y, (_Float16)acc1.z, (_Float16)acc1.w};

      // ---- GEMM2: H^T[256 x 16pts] = R . P^T, 16 j-tiles x (2 MFMAs, K=32) ----
      if (k < 2) {
#pragma unroll
        for (int t = 0; t < 16; ++t) {
          const half4_t rA = *(const half4_t*)&rwk[rwo + 576 * t];       // r = 4q+jj
          const half4_t rB = *(const half4_t*)&rwk[rwo + 576 * t + 16];  // r = 16+4q+jj
          float4_t hc = {0.f, 0.f, 0.f, 0.f};
          hc = __builtin_amdgcn_mfma_f32_16x16x16f16(rA, pfA, hc, 0, 0, 0);
          hc = __builtin_amdgcn_mfma_f32_16x16x16f16(rB, pfB, hc, 0, 0, 0);
          // D layout (j = 16t+4q+reg) == next GEMM1 B-frag layout. tanh+pack in-lane.
          half4_t h;
          h.x = (_Float16)fast_tanh(hc.x);
          h.y = (_Float16)fast_tanh(hc.y);
          h.z = (_Float16)fast_tanh(hc.z);
          h.w = (_Float16)fast_tanh(hc.w);
          hb[t] = h;
        }
      } else {
        // last block: fold end_w dot-product into the tanh epilogue in fp32
#pragma unroll
        for (int t = 0; t < 16; ++t) {
          const half4_t rA = *(const half4_t*)&rwk[rwo + 576 * t];
          const half4_t rB = *(const half4_t*)&rwk[rwo + 576 * t + 16];
          float4_t hc = {0.f, 0.f, 0.f, 0.f};
          hc = __builtin_amdgcn_mfma_f32_16x16x16f16(rA, pfA, hc, 0, 0, 0);
          hc = __builtin_amdgcn_mfma_f32_16x16x16f16(rB, pfB, hc, 0, 0, 0);
          const float4_t ev = *(const float4_t*)&sm.ew[t * 16 + wo];
          ssum += fast_tanh(hc.x) * ev.x + fast_tanh(hc.y) * ev.y
                + fast_tanh(hc.z) * ev.z + fast_tanh(hc.w) * ev.w;
        }
      }
    }
    // each lane holds the partial dot over its j-subset; reduce over the 4 quads
    ssum += __shfl_xor(ssum, 16);
    ssum += __shfl_xor(ssum, 32);
    if (lane < 16) out[n0 + m] = ssum + ebv;
  }
}

}  // namespace

extern "C" void kernel_launch(void* const* d_in, const int* in_sizes, int n_in,
                              void* d_out, int out_size, void* d_ws, size_t ws_size,
                              hipStream_t stream) {
  const float* xg  = (const float*)d_in[0];
  const float* tg  = (const float*)d_in[1];
  const float* sw  = (const float*)d_in[2];
  const float* sb  = (const float*)d_in[3];
  const float* ewp = (const float*)d_in[4];
  const float* ebp = (const float*)d_in[5];
  const float* c0  = (const float*)d_in[6];
  const float* c1  = (const float*)d_in[7];
  const float* c2  = (const float*)d_in[8];
  const float* r0  = (const float*)d_in[9];
  const float* r1  = (const float*)d_in[10];
  const float* r2  = (const float*)d_in[11];
  const float* a0  = (const float*)d_in[12];
  const float* a1  = (const float*)d_in[13];
  const float* a2  = (const float*)d_in[14];
  float* outp = (float*)d_out;

  const int n = in_sizes[0];  // 262144

  pinn_fused<<<256, 1024, 0, stream>>>(xg, tg, sw, sb, ewp, ebp,
                                       c0, c1, c2, r0, r1, r2, a0, a1, a2,
                                       outp, n);
}